// Round 4
// baseline (131.674 us; speedup 1.0000x reference)
//
#include <hip/hip_runtime.h>
#include <hip/hip_fp16.h>

static constexpr int BASE = 512;

typedef float f32x2 __attribute__((ext_vector_type(2)));
typedef float f32x4 __attribute__((ext_vector_type(4)));
typedef unsigned int u32x4 __attribute__((ext_vector_type(4)));

// half-element offsets of each level in the (h,w,16)-layout fp16 pyramid
// (used by build_levels, where the index is wave-uniform -> scalar load)
__constant__ int c_off[8] = {0, 4194304, 5242880, 5505024, 5570560, 5586944, 5591040, 5592064};
// total halves = 5592320 -> 11,184,640 bytes of ws
// levels 4..7 live at half-offset [5570560, 5592320) -> 43520 bytes: fits LDS.
static constexpr int LVL4_HALF = 5570560;
static constexpr int LVL4_BYTE = 11141120;      // LVL4_HALF * 2
static constexpr int SMEM_F4 = 2720;            // 43520 / 16

// ---------------- Kernel A1: transpose (C,512,512) fp32 -> (512,512,C) fp16 ----------------
__global__ void transpose_l0(const float* __restrict__ tex, __half* __restrict__ dst) {
    int pix = blockIdx.x * blockDim.x + threadIdx.x;   // grid sized exactly: 262144 threads
    float v[16];
#pragma unroll
    for (int c = 0; c < 16; ++c)
        v[c] = __builtin_nontemporal_load(tex + c * 262144 + pix);  // streamed once
    __half2 h[8];
#pragma unroll
    for (int i = 0; i < 8; ++i) h[i] = __floats2half2_rn(v[2 * i], v[2 * i + 1]);
    float4* o = (float4*)(dst + (size_t)pix * 16);
    o[0] = *(const float4*)&h[0];   // L0 is reused by A2+B: keep cached
    o[1] = *(const float4*)&h[4];
}

// convert one 32B texel (16 halves) to 16 floats
__device__ inline void load_texel16(const __half* p, float* f) {
    float4 r0 = ((const float4*)p)[0];
    float4 r1 = ((const float4*)p)[1];
    const __half2* h0 = (const __half2*)&r0;
    const __half2* h1 = (const __half2*)&r1;
#pragma unroll
    for (int i = 0; i < 4; ++i) {
        float2 a = __half22float2(h0[i]);
        f[2 * i] = a.x; f[2 * i + 1] = a.y;
        float2 b = __half22float2(h1[i]);
        f[8 + 2 * i] = b.x; f[9 + 2 * i] = b.y;
    }
}

// ---------------- Kernel A2: build levels 1..7 from fp16 L0 ----------------
// Reference resize (align_corners=False, pow2 scale) == 2x2 avg at
// yy=(y<<l)+(1<<(l-1))-1, association: (v00*.5+v10*.5)*.5+(v01*.5+v11*.5)*.5
__global__ void build_levels(const __half* __restrict__ l0, __half* __restrict__ ws) {
    int lev = blockIdx.y + 1;            // 1..7
    int w = BASE >> lev;
    int npix = w * w;
    int pix = blockIdx.x * blockDim.x + threadIdx.x;
    if (pix >= npix) return;
    int y = pix >> (9 - lev);
    int x = pix & (w - 1);
    int xx = (x << lev) + (1 << (lev - 1)) - 1;
    int yy = (y << lev) + (1 << (lev - 1)) - 1;
    const __half* b00 = l0 + (size_t)(yy * 512 + xx) * 16;
    float a[16], b[16], c[16], d[16];
    load_texel16(b00, a);                // (yy  , xx  )
    load_texel16(b00 + 16, b);           // (yy  , xx+1)
    load_texel16(b00 + 512 * 16, c);     // (yy+1, xx  )
    load_texel16(b00 + 512 * 16 + 16, d);// (yy+1, xx+1)
    __half2 r[8];
#pragma unroll
    for (int i = 0; i < 8; ++i) {
        float r0 = (a[2 * i] * 0.5f + c[2 * i] * 0.5f) * 0.5f +
                   (b[2 * i] * 0.5f + d[2 * i] * 0.5f) * 0.5f;
        float r1 = (a[2 * i + 1] * 0.5f + c[2 * i + 1] * 0.5f) * 0.5f +
                   (b[2 * i + 1] * 0.5f + d[2 * i + 1] * 0.5f) * 0.5f;
        r[i] = __floats2half2_rn(r0, r1);
    }
    float4* dst = (float4*)(ws + c_off[lev] + (size_t)pix * 16);
    dst[0] = *(const float4*)&r[0];
    dst[1] = *(const float4*)&r[4];
}

// ---------------- Kernel B: trilinear mip sampling ----------------
// 2 threads per query; thread q handles channels [8q, 8q+8).
// Levels 4..7 (43.5 KB = 50% of all texel gathers) are staged in LDS once per
// persistent block. Every thread issues all 8 global loads, but LDS-resident
// lanes read byte 0 (wave-wide broadcast line ~ free); all threads issue LDS
// reads with global lanes at LDS byte 0 (broadcast ~ free); cndmask selects.
// -> global gather line-requests drop ~2x, no divergent branches.
__global__ __launch_bounds__(512, 6)
void sample_kernel(const float2* __restrict__ uv, const float* __restrict__ p,
                   const __half* __restrict__ ws, float* __restrict__ out, int total) {
    __shared__ __align__(16) float4 smem[SMEM_F4];

    // ---- stage levels 4..7 into LDS (coalesced, L2/L3-resident source) ----
    {
        const float4* src = (const float4*)(ws + LVL4_HALF);
        for (int i = threadIdx.x; i < SMEM_F4; i += 512) smem[i] = src[i];
    }
    __syncthreads();

    // ---- SRSRC descriptor for ws (stride=0, raw, bounds-check disabled) ----
    u32x4 srsrc;
    unsigned long long wsa = (unsigned long long)(const void*)ws;
    srsrc.x = (unsigned int)wsa;
    srsrc.y = (unsigned int)(wsa >> 32);   // stride bits zero
    srsrc.z = 0xFFFFFFFFu;                 // disable range check
    srsrc.w = 0x00020000u;                 // raw dword buffer

    const char* sb = (const char*)smem;
    int stride = gridDim.x * blockDim.x;

    for (int tid = blockIdx.x * blockDim.x + threadIdx.x; tid < total; tid += stride) {
        int n = tid >> 1;
        int q = tid & 1;

        f32x2 uvn = __builtin_nontemporal_load((const f32x2*)uv + n);
        float pp = __builtin_nontemporal_load(p + n);
        float gx = 2.0f * uvn.x - 1.0f;
        float gy = 2.0f * uvn.y - 1.0f;

        float lf = pp * 7.0f;
        int l0 = min((int)lf, 7);            // lf >= 0
        int l1 = min(l0 + 1, 7);
        float alpha = lf - (float)l0;

        int goff[8];       // global byte offsets (0 for LDS-resident lanes)
        int loff[8];       // LDS byte offsets (0 for global lanes)
        float wgt[8];
        bool sel[2];
        int ls2[2] = {l0, l1};
        float lw2[2] = {1.0f - alpha, alpha};
#pragma unroll
        for (int k = 0; k < 2; ++k) {
            int l = ls2[k];
            int w = BASE >> l;
            float wm1 = (float)(w - 1);
            float x = fminf(fmaxf((gx + 1.0f) * 0.5f * wm1, 0.0f), wm1);
            float y = fminf(fmaxf((gy + 1.0f) * 0.5f * wm1, 0.0f), wm1);
            int x0 = min((int)x, w - 1);
            int y0 = min((int)y, w - 1);
            int x1 = min(x0 + 1, w - 1);
            int y1 = min(y0 + 1, w - 1);
            float fx = x - (float)x0;
            float fy = y - (float)y0;
            // level byte offset: halves = (0x555555 >> (24-2l)) << (24-2l)
            int sh = 24 - 2 * l;
            int offh = (0x555555 >> sh) << sh;
            bool s = l >= 4;
            sel[k] = s;
            int base = offh * 2 + q * 16;    // byte offset of this thread's half-texel
            int ob0 = base + (y0 * w + x0) * 32;
            int ob1 = base + (y0 * w + x1) * 32;
            int ob2 = base + (y1 * w + x0) * 32;
            int ob3 = base + (y1 * w + x1) * 32;
            goff[4 * k + 0] = s ? 0 : ob0;
            goff[4 * k + 1] = s ? 0 : ob1;
            goff[4 * k + 2] = s ? 0 : ob2;
            goff[4 * k + 3] = s ? 0 : ob3;
            loff[4 * k + 0] = s ? (ob0 - LVL4_BYTE) : 0;
            loff[4 * k + 1] = s ? (ob1 - LVL4_BYTE) : 0;
            loff[4 * k + 2] = s ? (ob2 - LVL4_BYTE) : 0;
            loff[4 * k + 3] = s ? (ob3 - LVL4_BYTE) : 0;
            wgt[4 * k + 0] = (1.0f - fx) * (1.0f - fy) * lw2[k];
            wgt[4 * k + 1] = fx * (1.0f - fy) * lw2[k];
            wgt[4 * k + 2] = (1.0f - fx) * fy * lw2[k];
            wgt[4 * k + 3] = fx * fy * lw2[k];
        }

        // ---- issue all 8 global loads; wait for the first 4 inside the asm ----
        float4 r0, r1, r2, r3, r4, r5, r6, r7;
        asm volatile(
            "buffer_load_dwordx4 %0, %8, %16, 0 offen\n\t"
            "buffer_load_dwordx4 %1, %9, %16, 0 offen\n\t"
            "buffer_load_dwordx4 %2, %10, %16, 0 offen\n\t"
            "buffer_load_dwordx4 %3, %11, %16, 0 offen\n\t"
            "buffer_load_dwordx4 %4, %12, %16, 0 offen\n\t"
            "buffer_load_dwordx4 %5, %13, %16, 0 offen\n\t"
            "buffer_load_dwordx4 %6, %14, %16, 0 offen\n\t"
            "buffer_load_dwordx4 %7, %15, %16, 0 offen\n\t"
            "s_waitcnt vmcnt(4)"
            : "=&v"(r0), "=&v"(r1), "=&v"(r2), "=&v"(r3),
              "=&v"(r4), "=&v"(r5), "=&v"(r6), "=&v"(r7)
            : "v"(goff[0]), "v"(goff[1]), "v"(goff[2]), "v"(goff[3]),
              "v"(goff[4]), "v"(goff[5]), "v"(goff[6]), "v"(goff[7]),
              "s"(srsrc));

        float acc[8];
#pragma unroll
        for (int j = 0; j < 8; ++j) acc[j] = 0.0f;

#define ACCUM_SEL(RG, LOFF, I, S)                              \
    {                                                          \
        float4 vl_ = *(const float4*)(sb + (LOFF));            \
        float4 v_ = (S) ? vl_ : (RG);                          \
        const __half2* h = (const __half2*)&v_;                \
        float wv = wgt[I];                                     \
        _Pragma("unroll")                                      \
        for (int j = 0; j < 4; ++j) {                          \
            float2 a = __half22float2(h[j]);                   \
            acc[2 * j]     += a.x * wv;                        \
            acc[2 * j + 1] += a.y * wv;                        \
        }                                                      \
    }
        // group 0 (level l0): global halves ready after vmcnt(4)
        ACCUM_SEL(r0, loff[0], 0, sel[0])
        ACCUM_SEL(r1, loff[1], 1, sel[0])
        ACCUM_SEL(r2, loff[2], 2, sel[0])
        ACCUM_SEL(r3, loff[3], 3, sel[0])

        // wait for the remaining 4 global loads; pin consumers below (rule #18)
        asm volatile("s_waitcnt vmcnt(0)" ::: "memory");
        __builtin_amdgcn_sched_barrier(0);

        // group 1 (level l1)
        ACCUM_SEL(r4, loff[4], 4, sel[1])
        ACCUM_SEL(r5, loff[5], 5, sel[1])
        ACCUM_SEL(r6, loff[6], 6, sel[1])
        ACCUM_SEL(r7, loff[7], 7, sel[1])
#undef ACCUM_SEL

        // output is streamed once: nt store keeps 64MB of write-allocate
        // traffic out of the per-XCD L2s
        f32x4 o0 = {acc[0], acc[1], acc[2], acc[3]};
        f32x4 o1 = {acc[4], acc[5], acc[6], acc[7]};
        f32x4* o = (f32x4*)(out + (size_t)n * 16 + 8 * q);
        __builtin_nontemporal_store(o0, o);
        __builtin_nontemporal_store(o1, o + 1);
    }
}

extern "C" void kernel_launch(void* const* d_in, const int* in_sizes, int n_in,
                              void* d_out, int out_size, void* d_ws, size_t ws_size,
                              hipStream_t stream) {
    const float* uv  = (const float*)d_in[0];
    const float* p   = (const float*)d_in[1];
    const float* tex = (const float*)d_in[2];
    float* out = (float*)d_out;
    __half* ws = (__half*)d_ws;
    int N = in_sizes[1];

    // A1: transpose+convert base level into ws (262144 pixels, exact grid)
    transpose_l0<<<262144 / 256, 256, 0, stream>>>(tex, ws);

    // A2: build levels 1..7
    dim3 gA2(256, 7);
    build_levels<<<gA2, 256, 0, stream>>>(ws, ws);

    // B: sample — persistent grid: 3 blocks/CU x 256 CU, grid-stride over 2N
    long long total = (long long)N * 2;
    int blocks = (int)min((long long)768, (total + 511) / 512);
    sample_kernel<<<blocks, 512, 0, stream>>>((const float2*)uv, p, ws, out, (int)total);
}